// Round 6
// baseline (15786.455 us; speedup 1.0000x reference)
//
#include <hip/hip_runtime.h>
#include <hip/hip_bf16.h>

#define TSTEPS 4096
#define BATCH 16
#define HID 1024
#define DIN 147
#define KIN 160
#define KC  (HID + KIN)      /* 1184 = 37*32 : weight row = [w_hh(1024) | w_ih(160)] */
#define NWG 64               /* GRU workgroups: 1 col-block (16 cols) x 3 gate-waves each */
#define NFC 160              /* FC worker workgroups fused into the same launch */
#define NCLS 256
#define FCN 1024
#define KFC 576

typedef __attribute__((ext_vector_type(8))) short short8;
typedef __attribute__((ext_vector_type(4))) float floatx4;

__device__ __forceinline__ unsigned short f2b(float f) {
  __hip_bfloat16 h = __float2bfloat16(f);
  return *reinterpret_cast<unsigned short*>(&h);
}

#define GLOAD_LDS16(g, l) __builtin_amdgcn_global_load_lds( \
    (const __attribute__((address_space(1))) void*)(g), \
    (__attribute__((address_space(3))) void*)(l), 16, 0, 0)

// H layout (blocked): H[t][cb(64)][row(16)][col(16)] bf16.
//   tile(t) = 32KB; block cb = 512B contiguous = 4 FULL 128B lines, written by
//   exactly one producer WG with plain system-scope stores (R4-proven fastest).
//   addr(t, cb, r, c) = H + t*16384 + cb*256 + r*16 + c   (ushort units)

// ---------------- pack: Xg (x-part bf16), aux bf16, H[0]=0, flags=0 ----------------
__global__ void k_pack(const float* __restrict__ x, const float* __restrict__ feat,
                       const float* __restrict__ aux1, const float* __restrict__ aux2,
                       const float* __restrict__ aux3,
                       unsigned short* __restrict__ Xg, unsigned short* __restrict__ H,
                       unsigned short* __restrict__ a2b, unsigned short* __restrict__ a3b,
                       unsigned int* __restrict__ flags) {
  const int t = blockIdx.x;
  const int tid = threadIdx.x;
  for (int i = tid; i < BATCH * KIN; i += 256) {
    int b = i / KIN, k = i - b * KIN;
    float v = 0.f;
    if (k < 80)       v = feat[((size_t)b * TSTEPS + t) * 80 + k];
    else if (k < 144) v = aux1[((size_t)b * TSTEPS + t) * 64 + (k - 80)];
    else if (k < 147) v = x[((size_t)b * TSTEPS + t) * 3 + (k - 144)];
    Xg[((size_t)t * BATCH + b) * KIN + k] = f2b(v);
  }
  for (int i = tid; i < BATCH * 64; i += 256) {
    int b = i >> 6, k = i & 63;
    a2b[(size_t)t * (BATCH * 64) + i] = f2b(aux2[((size_t)b * TSTEPS + t) * 64 + k]);
    a3b[(size_t)t * (BATCH * 64) + i] = f2b(aux3[((size_t)b * TSTEPS + t) * 64 + k]);
  }
  if (t == 0) {
    for (int i = tid; i < BATCH * HID; i += 256) H[i] = 0;  // h_{-1} = 0 (layout-agnostic)
    for (int i = tid; i < 256; i += 256) flags[i] = 0u;     // dense flags (64 used)
  }
}

// ---------------- weight convert: Wc=[w_hh|w_ih] bf16, w1..w4 bf16 ----------------
__global__ void k_wconv(const float* __restrict__ w_ih, const float* __restrict__ w_hh,
                        const float* __restrict__ w1, const float* __restrict__ w2,
                        const float* __restrict__ w3, const float* __restrict__ w4,
                        unsigned short* __restrict__ Wc,
                        unsigned short* __restrict__ w1b, unsigned short* __restrict__ w2b,
                        unsigned short* __restrict__ w3b, unsigned short* __restrict__ w4b) {
  const int bid = blockIdx.x, tid = threadIdx.x;
  if (bid < 3072) {
    const int row = bid;
    for (int k = tid; k < KC; k += 256) {
      float v = 0.f;
      if (k < HID) v = w_hh[(size_t)row * HID + k];
      else if (k < HID + DIN) v = w_ih[(size_t)row * DIN + (k - HID)];
      Wc[(size_t)row * KC + k] = f2b(v);
    }
  } else if (bid < 4096) {
    const int row = bid - 3072;
    for (int k = tid; k < KFC; k += 256) w1b[(size_t)row * KFC + k] = f2b(w1[(size_t)row * KFC + k]);
  } else if (bid < 4352) {
    const int row = bid - 4096;
    for (int k = tid; k < FCN; k += 256) w2b[(size_t)row * FCN + k] = f2b(w2[(size_t)row * FCN + k]);
  } else if (bid < 5376) {
    const int row = bid - 4352;
    for (int k = tid; k < KFC; k += 256) w3b[(size_t)row * KFC + k] = f2b(w3[(size_t)row * KFC + k]);
  } else {
    const int row = bid - 5376;
    for (int k = tid; k < FCN; k += 256) w4b[(size_t)row * FCN + k] = f2b(w4[(size_t)row * FCN + k]);
  }
}

// ---------------- fused persistent kernel ----------------
// Blocks 0..63   : GRU (3 waves = gates r/z/n of one 16-col block). Protocol = R4
//                  exactly (plain system-scope h stores -> vmcnt(0) -> flag store;
//                  wave-1 polls then bulk global_load_lds stage). Only change:
//                  flags are DENSE (4B stride, 2 lines) to cut poll congestion.
// Blocks 64..223 : FC workers. Task idx = (t, branch); worker w handles
//                  idx = w, w+NFC, ... For time t it needs H tile (t+1), i.e.
//                  all flags >= t+1 — same first-touch-after-flag freshness
//                  argument as the GRU consumers (lines written once, read only
//                  after flag observed system-scope). Tasks lag the GRU frontier
//                  by ~80 steps per worker stride, so polls almost always pass;
//                  s_sleep paces the rare waits to keep IF traffic off the GRU
//                  critical path. FC runs entirely in the GRU latency shadow.
__launch_bounds__(192, 1)
__global__ void k_gru(const unsigned short* __restrict__ Wc,
                      const float* __restrict__ b_ih, const float* __restrict__ b_hh,
                      const unsigned short* __restrict__ Xg,
                      unsigned short* __restrict__ H,
                      unsigned int* __restrict__ flags,
                      const unsigned short* __restrict__ a2b, const unsigned short* __restrict__ a3b,
                      const unsigned short* __restrict__ w1b, const unsigned short* __restrict__ w2b,
                      const unsigned short* __restrict__ w3b, const unsigned short* __restrict__ w4b,
                      const float* __restrict__ b1, const float* __restrict__ b2,
                      const float* __restrict__ b3, const float* __restrict__ b4,
                      float* __restrict__ out) {
  __shared__ __align__(16) unsigned char smem[51712];   // union: GRU 36.3KB / FC 51.7KB

  const int tid  = threadIdx.x;
  const int wave = tid >> 6;
  const int lane = tid & 63;
  const int cn   = lane & 15;
  const int quad = lane >> 4;

  if (blockIdx.x < NWG) {
    // ================= GRU path =================
    const int wg   = blockIdx.x;        // 0..63 == col-block
    const int gate = wave;              // 0=r, 1=z, 2=n
    const int grow = gate * HID + wg * 16 + cn;

    unsigned short* lh = reinterpret_cast<unsigned short*>(smem);          // 32KB tile
    float* lds_z  = reinterpret_cast<float*>(smem + 32768);
    float* lds_hn = reinterpret_cast<float*>(smem + 32768 + 1024);
    float* lds_xn = reinterpret_cast<float*>(smem + 32768 + 2048);
    unsigned* lds_hout = reinterpret_cast<unsigned*>(smem + 32768 + 3072); // 512B bounce

    // resident B-fragments: 37 * 16B = 148 regs
    short8 wf[37];
    {
      const short8* wptr = reinterpret_cast<const short8*>(Wc + (size_t)grow * KC);
#pragma unroll
      for (int ks = 0; ks < 37; ks++) wf[ks] = wptr[ks * 4 + quad];
    }
    const float bih = b_ih[grow];
    const float bhh = b_hh[grow];
    const float brz = bih + bhh;

    float hprev[4] = {0.f, 0.f, 0.f, 0.f};  // gate-0 wave: fp32 carried state
    const int swz = (cn & 7) << 3;   // read-side XOR, ushort units (16B granules)

    for (int t = 0; t < TSTEPS; t++) {
      // x-part (k in [1024,1184)): no h dependency -> before poll/barrier
      floatx4 accx = {0.f, 0.f, 0.f, 0.f};
      {
        const short8* xptr = reinterpret_cast<const short8*>(Xg + ((size_t)t * BATCH + cn) * KIN);
        short8 ax[5];
#pragma unroll
        for (int ks = 0; ks < 5; ks++) ax[ks] = xptr[ks * 4 + quad];
#pragma unroll
        for (int ks = 0; ks < 5; ks++)
          accx = __builtin_amdgcn_mfma_f32_16x16x32_bf16(ax[ks], wf[32 + ks], accx, 0, 0, 0);
      }

      // wave 1: poll all 64 flags (dense: 2 lines), then stage the 32KB H tile.
      if (wave == 1) {
        const unsigned need = (unsigned)t;   // flag[wg] == t  means step t-1 done
        for (;;) {
          unsigned f = __hip_atomic_load(&flags[lane], __ATOMIC_RELAXED,
                                         __HIP_MEMORY_SCOPE_SYSTEM);
          if (__ballot(f >= need) == ~0ull) break;
        }
        const char* Ht = reinterpret_cast<const char*>(H + (size_t)t * BATCH * HID);
        char* lbase = reinterpret_cast<char*>(lh);
#pragma unroll
        for (int i = 0; i < 32; i++) {
          const int d  = (i << 10) + (lane << 4);       // dest byte in tile (linear)
          const int r  = d >> 11;                        // logical row
          const int lb = (d & 2047) ^ ((r & 7) << 4);    // logical byte in row (inv-swz)
          const char* g = Ht + ((lb >> 5) << 9) + (r << 5) + (lb & 31);   // blocked src
          GLOAD_LDS16(g, lbase + (i << 10));
        }
        asm volatile("s_waitcnt vmcnt(0)" ::: "memory");
      }
      asm volatile("" ::: "memory");
      __syncthreads();   // B1: tile staged; also h_{t-1} visible + LDS WAR protection

      floatx4 acc0 = {0.f, 0.f, 0.f, 0.f};
      floatx4 acc1 = {0.f, 0.f, 0.f, 0.f};
      {
        const int rb = cn * 1024;
#pragma unroll
        for (int ks = 0; ks < 32; ks += 2) {
          short8 a0 = *reinterpret_cast<const short8*>(&lh[rb + (((ks    ) * 32 + quad * 8) ^ swz)]);
          short8 a1 = *reinterpret_cast<const short8*>(&lh[rb + (((ks + 1) * 32 + quad * 8) ^ swz)]);
          acc0 = __builtin_amdgcn_mfma_f32_16x16x32_bf16(a0, wf[ks],     acc0, 0, 0, 0);
          acc1 = __builtin_amdgcn_mfma_f32_16x16x32_bf16(a1, wf[ks + 1], acc1, 0, 0, 0);
        }
      }

      float rr[4];
      if (gate == 0) {
#pragma unroll
        for (int j = 0; j < 4; j++) {
          float g = acc0[j] + acc1[j] + accx[j] + brz;
          rr[j] = __builtin_amdgcn_rcpf(1.f + __expf(-g));
        }
      } else if (gate == 1) {
#pragma unroll
        for (int j = 0; j < 4; j++) {
          float g = acc0[j] + acc1[j] + accx[j] + brz;
          lds_z[(quad * 4 + j) * 16 + cn] = __builtin_amdgcn_rcpf(1.f + __expf(-g));
        }
      } else {
#pragma unroll
        for (int j = 0; j < 4; j++) {
          int idx = (quad * 4 + j) * 16 + cn;
          lds_hn[idx] = acc0[j] + acc1[j] + bhh;  // w_hh part + b_hh
          lds_xn[idx] = accx[j] + bih;            // w_ih part + b_ih
        }
      }
      __syncthreads();   // B2: gate values ready

      if (gate == 0) {
#pragma unroll
        for (int j = 0; j < 4; j++) {
          int idx = (quad * 4 + j) * 16 + cn;
          float z = lds_z[idx];
          float a = lds_xn[idx] + rr[j] * lds_hn[idx];
          float e2 = __expf(2.f * a);
          float n = 1.f - 2.f * __builtin_amdgcn_rcpf(e2 + 1.f);   // tanh(a)
          float h = (1.f - z) * n + z * hprev[j];
          hprev[j] = h;
          unsigned hv = (unsigned)f2b(h);
          unsigned pv = __shfl_xor(hv, 1);
          if ((cn & 1) == 0)
            lds_hout[(quad * 4 + j) * 8 + (cn >> 1)] = hv | (pv << 16);
        }
        // 8B contiguous per lane -> 4 FULL 128B lines, plain system-scope (R4)
        unsigned long long v8 = reinterpret_cast<unsigned long long*>(lds_hout)[lane];
        unsigned long long* dst =
            reinterpret_cast<unsigned long long*>(H + (size_t)(t + 1) * BATCH * HID + wg * 256) + lane;
        __hip_atomic_store(dst, v8, __ATOMIC_RELAXED, __HIP_MEMORY_SCOPE_SYSTEM);
        asm volatile("s_waitcnt vmcnt(0)" ::: "memory");  // data committed before flag
        if (lane == 0)
          __hip_atomic_store(&flags[wg], (unsigned)(t + 1), __ATOMIC_RELAXED,
                             __HIP_MEMORY_SCOPE_SYSTEM);
      }
    }
  } else {
    // ================= FC worker path =================
    const int w = blockIdx.x - NWG;
    unsigned short (*lA)[584] = reinterpret_cast<unsigned short(*)[584]>(smem);
    float (*lZ)[260] = reinterpret_cast<float(*)[260]>(smem);
    unsigned short (*lO)[1032] = reinterpret_cast<unsigned short(*)[1032]>(smem + 18688);

    for (int idx = w; idx < TSTEPS * 2; idx += NFC) {
      const int t  = idx >> 1;
      const int br = idx & 1;
      const unsigned short* wAp = br ? w3b : w1b;
      const unsigned short* wBp = br ? w4b : w2b;
      const float* bA = br ? b3 : b1;
      const float* bB = br ? b4 : b2;
      const unsigned short* aux = br ? a3b : a2b;
      float* outp = out + (size_t)br * BATCH * TSTEPS * NCLS;

      // wait for h_t (tile t+1): all flags >= t+1, sleep-paced (usually passes)
      if (wave == 0) {
        const unsigned need = (unsigned)(t + 1);
        for (;;) {
          unsigned f = __hip_atomic_load(&flags[lane], __ATOMIC_RELAXED,
                                         __HIP_MEMORY_SCOPE_SYSTEM);
          if (__ballot(f >= need) == ~0ull) break;
          __builtin_amdgcn_s_sleep(32);
        }
      }
      __syncthreads();

      // stage A1 = [h_t(512) | aux(64)], rows b=0..15 (blocked H tile t+1)
      {
        const unsigned short* hb = H + (size_t)(t + 1) * BATCH * HID;
        for (int cid = tid; cid < 16 * 72; cid += 192) {
          int r = cid / 72, off = (cid - r * 72) * 8;
          uint4 v;
          if (off < 512)
            v = *reinterpret_cast<const uint4*>(hb + ((size_t)(br * 32 + (off >> 4))) * 256 + r * 16 + (off & 15));
          else
            v = *reinterpret_cast<const uint4*>(aux + ((size_t)t * 16 + r) * 64 + (off - 512));
          *reinterpret_cast<uint4*>(&lA[r][off]) = v;
        }
      }
      __syncthreads();

      // GEMM1: (16 x 576) @ (576 x 1024), 64 col-tiles striped over 3 waves
      {
        short8 af[18];
#pragma unroll
        for (int ks = 0; ks < 18; ks++)
          af[ks] = *reinterpret_cast<const short8*>(&lA[cn][ks * 32 + quad * 8]);

        for (int nt = wave; nt < 64; nt += 3) {
          const int colg = nt * 16 + cn;
          const short8* bptr = reinterpret_cast<const short8*>(wAp + (size_t)colg * KFC);
          floatx4 acc = {0.f, 0.f, 0.f, 0.f};
#pragma unroll
          for (int ks = 0; ks < 18; ks++)
            acc = __builtin_amdgcn_mfma_f32_16x16x32_bf16(af[ks], bptr[ks * 4 + quad], acc, 0, 0, 0);
          const float bias = bA[colg];
#pragma unroll
          for (int j = 0; j < 4; j++) {
            float v = acc[j] + bias;
            v = v > 0.f ? v : 0.f;                 // relu
            lO[quad * 4 + j][colg] = f2b(v);
          }
        }
      }
      __syncthreads();

      // GEMM2: (16 x 1024) @ (1024 x 256), 16 col-tiles striped over 3 waves
      {
        short8 of[32];
#pragma unroll
        for (int ks = 0; ks < 32; ks++)
          of[ks] = *reinterpret_cast<const short8*>(&lO[cn][ks * 32 + quad * 8]);

        for (int nt = wave; nt < 16; nt += 3) {
          const int cls = nt * 16 + cn;
          const short8* bptr = reinterpret_cast<const short8*>(wBp + (size_t)cls * FCN);
          floatx4 acc = {0.f, 0.f, 0.f, 0.f};
#pragma unroll
          for (int ks = 0; ks < 32; ks++)
            acc = __builtin_amdgcn_mfma_f32_16x16x32_bf16(of[ks], bptr[ks * 4 + quad], acc, 0, 0, 0);
          const float bias = bB[cls];
#pragma unroll
          for (int j = 0; j < 4; j++)
            lZ[quad * 4 + j][cls] = acc[j] + bias;
        }
      }
      __syncthreads();

      // log_softmax per row: 128 threads = 16 rows x 8 threads, 32 vals each
      if (tid < 128) {
        const int r = tid >> 3, j = tid & 7;
        float vals[32];
        float m = -3.4e38f;
#pragma unroll
        for (int i = 0; i < 32; i++) {
          float v = lZ[r][j + 8 * i];
          vals[i] = v;
          m = fmaxf(m, v);
        }
#pragma unroll
        for (int s = 4; s > 0; s >>= 1) m = fmaxf(m, __shfl_xor(m, s, 8));
        float ssum = 0.f;
#pragma unroll
        for (int i = 0; i < 32; i++) ssum += __expf(vals[i] - m);
#pragma unroll
        for (int s = 4; s > 0; s >>= 1) ssum += __shfl_xor(ssum, s, 8);
        const float lse = m + __logf(ssum);
        float* orow = outp + ((size_t)r * TSTEPS + t) * NCLS;
#pragma unroll
        for (int i = 0; i < 32; i++) orow[j + 8 * i] = vals[i] - lse;
      }
      __syncthreads();   // protect lA/lZ reuse across loop iterations
    }
  }
}

extern "C" void kernel_launch(void* const* d_in, const int* in_sizes, int n_in,
                              void* d_out, int out_size, void* d_ws, size_t ws_size,
                              hipStream_t stream) {
  const float* x    = (const float*)d_in[0];
  const float* feat = (const float*)d_in[1];
  const float* aux1 = (const float*)d_in[2];
  const float* aux2 = (const float*)d_in[3];
  const float* aux3 = (const float*)d_in[4];
  const float* w_ih = (const float*)d_in[5];
  const float* w_hh = (const float*)d_in[6];
  const float* b_ih = (const float*)d_in[7];
  const float* b_hh = (const float*)d_in[8];
  const float* w1   = (const float*)d_in[9];
  const float* b1   = (const float*)d_in[10];
  const float* w2   = (const float*)d_in[11];
  const float* b2   = (const float*)d_in[12];
  const float* w3   = (const float*)d_in[13];
  const float* b3   = (const float*)d_in[14];
  const float* w4   = (const float*)d_in[15];
  const float* b4   = (const float*)d_in[16];
  float* out = (float*)d_out;

  char* p = (char*)d_ws;
  unsigned short* H   = (unsigned short*)p; p += (size_t)(TSTEPS + 1) * BATCH * HID * 2;
  unsigned short* Xg  = (unsigned short*)p; p += (size_t)TSTEPS * BATCH * KIN * 2;
  unsigned int*  flags = (unsigned int*)p;  p += (size_t)TSTEPS * 4;
  unsigned short* Wc  = (unsigned short*)p; p += (size_t)3072 * KC * 2;
  unsigned short* w1b = (unsigned short*)p; p += (size_t)1024 * KFC * 2;
  unsigned short* w2b = (unsigned short*)p; p += (size_t)256 * FCN * 2;
  unsigned short* w3b = (unsigned short*)p; p += (size_t)1024 * KFC * 2;
  unsigned short* w4b = (unsigned short*)p; p += (size_t)256 * FCN * 2;
  unsigned short* a2b = (unsigned short*)p; p += (size_t)TSTEPS * BATCH * 64 * 2;
  unsigned short* a3b = (unsigned short*)p; p += (size_t)TSTEPS * BATCH * 64 * 2;

  if ((size_t)(p - (char*)d_ws) > ws_size) return;  // ws too small: fail loudly via absmax

  k_pack<<<TSTEPS, 256, 0, stream>>>(x, feat, aux1, aux2, aux3, Xg, H, a2b, a3b, flags);
  k_wconv<<<5632, 256, 0, stream>>>(w_ih, w_hh, w1, w2, w3, w4, Wc, w1b, w2b, w3b, w4b);
  k_gru<<<NWG + NFC, 192, 0, stream>>>(Wc, b_ih, b_hh, Xg, H, flags,
                                       a2b, a3b, w1b, w2b, w3b, w4b,
                                       b1, b2, b3, b4, out);
}

// Round 7
// 12985.437 us; speedup vs baseline: 1.2157x; 1.2157x over previous
//
#include <hip/hip_runtime.h>
#include <hip/hip_bf16.h>

#define TSTEPS 4096
#define BATCH 16
#define HID 1024
#define DIN 147
#define KIN 160
#define KC  (HID + KIN)      /* 1184 = 37*32 : weight row = [w_hh(1024) | w_ih(160)] */
#define NWG 64               /* GRU workgroups: 1 col-block (16 cols) x 3 gate-waves each */
#define NFC 160              /* FC worker workgroups fused into the same launch */
#define NCLS 256
#define FCN 1024
#define KFC 576
#define FRONTIER 512         /* uint index into flags[]: byte 2048, own cache line */

typedef __attribute__((ext_vector_type(8))) short short8;
typedef __attribute__((ext_vector_type(4))) float floatx4;

__device__ __forceinline__ unsigned short f2b(float f) {
  __hip_bfloat16 h = __float2bfloat16(f);
  return *reinterpret_cast<unsigned short*>(&h);
}

#define GLOAD_LDS16(g, l) __builtin_amdgcn_global_load_lds( \
    (const __attribute__((address_space(1))) void*)(g), \
    (__attribute__((address_space(3))) void*)(l), 16, 0, 0)

// H layout (blocked): H[t][cb(64)][row(16)][col(16)] bf16.
//   tile(t) = 32KB; block cb = 512B contiguous = 4 FULL 128B lines, written by
//   exactly one producer WG with plain system-scope stores (R4-proven fastest).

// ---------------- pack: Xg (x-part bf16), aux bf16, H[0]=0, flags=0 ----------------
__global__ void k_pack(const float* __restrict__ x, const float* __restrict__ feat,
                       const float* __restrict__ aux1, const float* __restrict__ aux2,
                       const float* __restrict__ aux3,
                       unsigned short* __restrict__ Xg, unsigned short* __restrict__ H,
                       unsigned short* __restrict__ a2b, unsigned short* __restrict__ a3b,
                       unsigned int* __restrict__ flags) {
  const int t = blockIdx.x;
  const int tid = threadIdx.x;
  for (int i = tid; i < BATCH * KIN; i += 256) {
    int b = i / KIN, k = i - b * KIN;
    float v = 0.f;
    if (k < 80)       v = feat[((size_t)b * TSTEPS + t) * 80 + k];
    else if (k < 144) v = aux1[((size_t)b * TSTEPS + t) * 64 + (k - 80)];
    else if (k < 147) v = x[((size_t)b * TSTEPS + t) * 3 + (k - 144)];
    Xg[((size_t)t * BATCH + b) * KIN + k] = f2b(v);
  }
  for (int i = tid; i < BATCH * 64; i += 256) {
    int b = i >> 6, k = i & 63;
    a2b[(size_t)t * (BATCH * 64) + i] = f2b(aux2[((size_t)b * TSTEPS + t) * 64 + k]);
    a3b[(size_t)t * (BATCH * 64) + i] = f2b(aux3[((size_t)b * TSTEPS + t) * 64 + k]);
  }
  if (t == 0) {
    for (int i = tid; i < BATCH * HID; i += 256) H[i] = 0;  // h_{-1} = 0 (layout-agnostic)
    for (int i = tid; i < TSTEPS; i += 256) flags[i] = 0u;  // covers flags + FRONTIER
  }
}

// ---------------- weight convert: Wc=[w_hh|w_ih] bf16, w1..w4 bf16 ----------------
__global__ void k_wconv(const float* __restrict__ w_ih, const float* __restrict__ w_hh,
                        const float* __restrict__ w1, const float* __restrict__ w2,
                        const float* __restrict__ w3, const float* __restrict__ w4,
                        unsigned short* __restrict__ Wc,
                        unsigned short* __restrict__ w1b, unsigned short* __restrict__ w2b,
                        unsigned short* __restrict__ w3b, unsigned short* __restrict__ w4b) {
  const int bid = blockIdx.x, tid = threadIdx.x;
  if (bid < 3072) {
    const int row = bid;
    for (int k = tid; k < KC; k += 256) {
      float v = 0.f;
      if (k < HID) v = w_hh[(size_t)row * HID + k];
      else if (k < HID + DIN) v = w_ih[(size_t)row * DIN + (k - HID)];
      Wc[(size_t)row * KC + k] = f2b(v);
    }
  } else if (bid < 4096) {
    const int row = bid - 3072;
    for (int k = tid; k < KFC; k += 256) w1b[(size_t)row * KFC + k] = f2b(w1[(size_t)row * KFC + k]);
  } else if (bid < 4352) {
    const int row = bid - 4096;
    for (int k = tid; k < FCN; k += 256) w2b[(size_t)row * FCN + k] = f2b(w2[(size_t)row * FCN + k]);
  } else if (bid < 5376) {
    const int row = bid - 4352;
    for (int k = tid; k < KFC; k += 256) w3b[(size_t)row * KFC + k] = f2b(w3[(size_t)row * KFC + k]);
  } else {
    const int row = bid - 5376;
    for (int k = tid; k < FCN; k += 256) w4b[(size_t)row * FCN + k] = f2b(w4[(size_t)row * FCN + k]);
  }
}

// ---------------- fused persistent kernel ----------------
// Blocks 0..63   : GRU — protocol BYTE-IDENTICAL to R4 (16B-stride flags, plain
//                  system-scope h stores -> vmcnt(0) -> flag store; wave-1 polls
//                  then bulk global_load_lds stage). Only addition: WG0's wave-1
//                  publishes frontier=t after its poll (it just proved all
//                  flags >= t) on a PRIVATE line — one store/step by one lane.
// Blocks 64..223 : FC workers. Poll ONLY the frontier line (read-only, sleep-
//                  paced) — zero traffic on the GRU flag lines. Task t runs when
//                  frontier >= t+1; H-tile freshness is transitive through the
//                  IF (producer drain -> flag -> WG0 observe -> frontier).
//                  224 blocks <= 256 CUs -> 1 block/CU (R6 occupancy confirmed),
//                  so FC never steals GRU CU issue slots.
__launch_bounds__(192, 1)
__global__ void k_gru(const unsigned short* __restrict__ Wc,
                      const float* __restrict__ b_ih, const float* __restrict__ b_hh,
                      const unsigned short* __restrict__ Xg,
                      unsigned short* __restrict__ H,
                      unsigned int* __restrict__ flags,
                      const unsigned short* __restrict__ a2b, const unsigned short* __restrict__ a3b,
                      const unsigned short* __restrict__ w1b, const unsigned short* __restrict__ w2b,
                      const unsigned short* __restrict__ w3b, const unsigned short* __restrict__ w4b,
                      const float* __restrict__ b1, const float* __restrict__ b2,
                      const float* __restrict__ b3, const float* __restrict__ b4,
                      float* __restrict__ out) {
  __shared__ __align__(16) unsigned char smem[51712];   // union: GRU 36.3KB / FC 51.7KB

  const int tid  = threadIdx.x;
  const int wave = tid >> 6;
  const int lane = tid & 63;
  const int cn   = lane & 15;
  const int quad = lane >> 4;

  if (blockIdx.x < NWG) {
    // ================= GRU path =================
    const int wg   = blockIdx.x;        // 0..63 == col-block
    const int gate = wave;              // 0=r, 1=z, 2=n
    const int grow = gate * HID + wg * 16 + cn;

    unsigned short* lh = reinterpret_cast<unsigned short*>(smem);          // 32KB tile
    float* lds_z  = reinterpret_cast<float*>(smem + 32768);
    float* lds_hn = reinterpret_cast<float*>(smem + 32768 + 1024);
    float* lds_xn = reinterpret_cast<float*>(smem + 32768 + 2048);
    unsigned* lds_hout = reinterpret_cast<unsigned*>(smem + 32768 + 3072); // 512B bounce

    // resident B-fragments: 37 * 16B = 148 regs
    short8 wf[37];
    {
      const short8* wptr = reinterpret_cast<const short8*>(Wc + (size_t)grow * KC);
#pragma unroll
      for (int ks = 0; ks < 37; ks++) wf[ks] = wptr[ks * 4 + quad];
    }
    const float bih = b_ih[grow];
    const float bhh = b_hh[grow];
    const float brz = bih + bhh;

    float hprev[4] = {0.f, 0.f, 0.f, 0.f};  // gate-0 wave: fp32 carried state
    const int swz = (cn & 7) << 3;   // read-side XOR, ushort units (16B granules)

    for (int t = 0; t < TSTEPS; t++) {
      // x-part (k in [1024,1184)): no h dependency -> before poll/barrier
      floatx4 accx = {0.f, 0.f, 0.f, 0.f};
      {
        const short8* xptr = reinterpret_cast<const short8*>(Xg + ((size_t)t * BATCH + cn) * KIN);
        short8 ax[5];
#pragma unroll
        for (int ks = 0; ks < 5; ks++) ax[ks] = xptr[ks * 4 + quad];
#pragma unroll
        for (int ks = 0; ks < 5; ks++)
          accx = __builtin_amdgcn_mfma_f32_16x16x32_bf16(ax[ks], wf[32 + ks], accx, 0, 0, 0);
      }

      // wave 1: poll all 64 flags (16B stride, R4 layout), then stage the H tile.
      if (wave == 1) {
        const unsigned need = (unsigned)t;   // flag[wg] == t  means step t-1 done
        for (;;) {
          unsigned f = __hip_atomic_load(&flags[lane * 4], __ATOMIC_RELAXED,
                                         __HIP_MEMORY_SCOPE_SYSTEM);
          if (__ballot(f >= need) == ~0ull) break;
        }
        // WG0 relays the proven frontier to the FC workers (private line)
        if (wg == 0 && lane == 0)
          __hip_atomic_store(&flags[FRONTIER], (unsigned)t, __ATOMIC_RELAXED,
                             __HIP_MEMORY_SCOPE_SYSTEM);
        const char* Ht = reinterpret_cast<const char*>(H + (size_t)t * BATCH * HID);
        char* lbase = reinterpret_cast<char*>(lh);
#pragma unroll
        for (int i = 0; i < 32; i++) {
          const int d  = (i << 10) + (lane << 4);       // dest byte in tile (linear)
          const int r  = d >> 11;                        // logical row
          const int lb = (d & 2047) ^ ((r & 7) << 4);    // logical byte in row (inv-swz)
          const char* g = Ht + ((lb >> 5) << 9) + (r << 5) + (lb & 31);   // blocked src
          GLOAD_LDS16(g, lbase + (i << 10));
        }
        asm volatile("s_waitcnt vmcnt(0)" ::: "memory");
      }
      asm volatile("" ::: "memory");
      __syncthreads();   // B1: tile staged; also h_{t-1} visible + LDS WAR protection

      floatx4 acc0 = {0.f, 0.f, 0.f, 0.f};
      floatx4 acc1 = {0.f, 0.f, 0.f, 0.f};
      {
        const int rb = cn * 1024;
#pragma unroll
        for (int ks = 0; ks < 32; ks += 2) {
          short8 a0 = *reinterpret_cast<const short8*>(&lh[rb + (((ks    ) * 32 + quad * 8) ^ swz)]);
          short8 a1 = *reinterpret_cast<const short8*>(&lh[rb + (((ks + 1) * 32 + quad * 8) ^ swz)]);
          acc0 = __builtin_amdgcn_mfma_f32_16x16x32_bf16(a0, wf[ks],     acc0, 0, 0, 0);
          acc1 = __builtin_amdgcn_mfma_f32_16x16x32_bf16(a1, wf[ks + 1], acc1, 0, 0, 0);
        }
      }

      float rr[4];
      if (gate == 0) {
#pragma unroll
        for (int j = 0; j < 4; j++) {
          float g = acc0[j] + acc1[j] + accx[j] + brz;
          rr[j] = __builtin_amdgcn_rcpf(1.f + __expf(-g));
        }
      } else if (gate == 1) {
#pragma unroll
        for (int j = 0; j < 4; j++) {
          float g = acc0[j] + acc1[j] + accx[j] + brz;
          lds_z[(quad * 4 + j) * 16 + cn] = __builtin_amdgcn_rcpf(1.f + __expf(-g));
        }
      } else {
#pragma unroll
        for (int j = 0; j < 4; j++) {
          int idx = (quad * 4 + j) * 16 + cn;
          lds_hn[idx] = acc0[j] + acc1[j] + bhh;  // w_hh part + b_hh
          lds_xn[idx] = accx[j] + bih;            // w_ih part + b_ih
        }
      }
      __syncthreads();   // B2: gate values ready

      if (gate == 0) {
#pragma unroll
        for (int j = 0; j < 4; j++) {
          int idx = (quad * 4 + j) * 16 + cn;
          float z = lds_z[idx];
          float a = lds_xn[idx] + rr[j] * lds_hn[idx];
          float e2 = __expf(2.f * a);
          float n = 1.f - 2.f * __builtin_amdgcn_rcpf(e2 + 1.f);   // tanh(a)
          float h = (1.f - z) * n + z * hprev[j];
          hprev[j] = h;
          unsigned hv = (unsigned)f2b(h);
          unsigned pv = __shfl_xor(hv, 1);
          if ((cn & 1) == 0)
            lds_hout[(quad * 4 + j) * 8 + (cn >> 1)] = hv | (pv << 16);
        }
        // 8B contiguous per lane -> 4 FULL 128B lines, plain system-scope (R4)
        unsigned long long v8 = reinterpret_cast<unsigned long long*>(lds_hout)[lane];
        unsigned long long* dst =
            reinterpret_cast<unsigned long long*>(H + (size_t)(t + 1) * BATCH * HID + wg * 256) + lane;
        __hip_atomic_store(dst, v8, __ATOMIC_RELAXED, __HIP_MEMORY_SCOPE_SYSTEM);
        asm volatile("s_waitcnt vmcnt(0)" ::: "memory");  // data committed before flag
        if (lane == 0)
          __hip_atomic_store(&flags[wg * 4], (unsigned)(t + 1), __ATOMIC_RELAXED,
                             __HIP_MEMORY_SCOPE_SYSTEM);
      }
    }

    // close the frontier: prove all flags reached TSTEPS, then publish it
    if (wg == 0 && wave == 1) {
      for (;;) {
        unsigned f = __hip_atomic_load(&flags[lane * 4], __ATOMIC_RELAXED,
                                       __HIP_MEMORY_SCOPE_SYSTEM);
        if (__ballot(f >= (unsigned)TSTEPS) == ~0ull) break;
      }
      if (lane == 0)
        __hip_atomic_store(&flags[FRONTIER], (unsigned)TSTEPS, __ATOMIC_RELAXED,
                           __HIP_MEMORY_SCOPE_SYSTEM);
    }
  } else {
    // ================= FC worker path =================
    const int w = blockIdx.x - NWG;
    unsigned short (*lA)[584] = reinterpret_cast<unsigned short(*)[584]>(smem);
    float (*lZ)[260] = reinterpret_cast<float(*)[260]>(smem);
    unsigned short (*lO)[1032] = reinterpret_cast<unsigned short(*)[1032]>(smem + 18688);

    for (int idx = w; idx < TSTEPS * 2; idx += NFC) {
      const int t  = idx >> 1;
      const int br = idx & 1;
      const unsigned short* wAp = br ? w3b : w1b;
      const unsigned short* wBp = br ? w4b : w2b;
      const float* bA = br ? b3 : b1;
      const float* bB = br ? b4 : b2;
      const unsigned short* aux = br ? a3b : a2b;
      float* outp = out + (size_t)br * BATCH * TSTEPS * NCLS;

      // wait for h_t (tile t+1) via the frontier relay only (read-only line)
      if (tid == 0) {
        const unsigned need = (unsigned)(t + 1);
        for (;;) {
          unsigned f = __hip_atomic_load(&flags[FRONTIER], __ATOMIC_RELAXED,
                                         __HIP_MEMORY_SCOPE_SYSTEM);
          if (f >= need) break;
          __builtin_amdgcn_s_sleep(64);
        }
      }
      __syncthreads();

      // stage A1 = [h_t(512) | aux(64)], rows b=0..15 (blocked H tile t+1)
      {
        const unsigned short* hb = H + (size_t)(t + 1) * BATCH * HID;
        for (int cid = tid; cid < 16 * 72; cid += 192) {
          int r = cid / 72, off = (cid - r * 72) * 8;
          uint4 v;
          if (off < 512)
            v = *reinterpret_cast<const uint4*>(hb + ((size_t)(br * 32 + (off >> 4))) * 256 + r * 16 + (off & 15));
          else
            v = *reinterpret_cast<const uint4*>(aux + ((size_t)t * 16 + r) * 64 + (off - 512));
          *reinterpret_cast<uint4*>(&lA[r][off]) = v;
        }
      }
      __syncthreads();

      // GEMM1: (16 x 576) @ (576 x 1024), 64 col-tiles striped over 3 waves
      {
        short8 af[18];
#pragma unroll
        for (int ks = 0; ks < 18; ks++)
          af[ks] = *reinterpret_cast<const short8*>(&lA[cn][ks * 32 + quad * 8]);

        for (int nt = wave; nt < 64; nt += 3) {
          const int colg = nt * 16 + cn;
          const short8* bptr = reinterpret_cast<const short8*>(wAp + (size_t)colg * KFC);
          floatx4 acc = {0.f, 0.f, 0.f, 0.f};
#pragma unroll
          for (int ks = 0; ks < 18; ks++)
            acc = __builtin_amdgcn_mfma_f32_16x16x32_bf16(af[ks], bptr[ks * 4 + quad], acc, 0, 0, 0);
          const float bias = bA[colg];
#pragma unroll
          for (int j = 0; j < 4; j++) {
            float v = acc[j] + bias;
            v = v > 0.f ? v : 0.f;                 // relu
            lO[quad * 4 + j][colg] = f2b(v);
          }
        }
      }
      __syncthreads();

      // GEMM2: (16 x 1024) @ (1024 x 256), 16 col-tiles striped over 3 waves
      {
        short8 of[32];
#pragma unroll
        for (int ks = 0; ks < 32; ks++)
          of[ks] = *reinterpret_cast<const short8*>(&lO[cn][ks * 32 + quad * 8]);

        for (int nt = wave; nt < 16; nt += 3) {
          const int cls = nt * 16 + cn;
          const short8* bptr = reinterpret_cast<const short8*>(wBp + (size_t)cls * FCN);
          floatx4 acc = {0.f, 0.f, 0.f, 0.f};
#pragma unroll
          for (int ks = 0; ks < 32; ks++)
            acc = __builtin_amdgcn_mfma_f32_16x16x32_bf16(of[ks], bptr[ks * 4 + quad], acc, 0, 0, 0);
          const float bias = bB[cls];
#pragma unroll
          for (int j = 0; j < 4; j++)
            lZ[quad * 4 + j][cls] = acc[j] + bias;
        }
      }
      __syncthreads();

      // log_softmax per row: 128 threads = 16 rows x 8 threads, 32 vals each
      if (tid < 128) {
        const int r = tid >> 3, j = tid & 7;
        float vals[32];
        float m = -3.4e38f;
#pragma unroll
        for (int i = 0; i < 32; i++) {
          float v = lZ[r][j + 8 * i];
          vals[i] = v;
          m = fmaxf(m, v);
        }
#pragma unroll
        for (int s = 4; s > 0; s >>= 1) m = fmaxf(m, __shfl_xor(m, s, 8));
        float ssum = 0.f;
#pragma unroll
        for (int i = 0; i < 32; i++) ssum += __expf(vals[i] - m);
#pragma unroll
        for (int s = 4; s > 0; s >>= 1) ssum += __shfl_xor(ssum, s, 8);
        const float lse = m + __logf(ssum);
        float* orow = outp + ((size_t)r * TSTEPS + t) * NCLS;
#pragma unroll
        for (int i = 0; i < 32; i++) orow[j + 8 * i] = vals[i] - lse;
      }
      __syncthreads();   // protect lA/lZ reuse across loop iterations
    }
  }
}

extern "C" void kernel_launch(void* const* d_in, const int* in_sizes, int n_in,
                              void* d_out, int out_size, void* d_ws, size_t ws_size,
                              hipStream_t stream) {
  const float* x    = (const float*)d_in[0];
  const float* feat = (const float*)d_in[1];
  const float* aux1 = (const float*)d_in[2];
  const float* aux2 = (const float*)d_in[3];
  const float* aux3 = (const float*)d_in[4];
  const float* w_ih = (const float*)d_in[5];
  const float* w_hh = (const float*)d_in[6];
  const float* b_ih = (const float*)d_in[7];
  const float* b_hh = (const float*)d_in[8];
  const float* w1   = (const float*)d_in[9];
  const float* b1   = (const float*)d_in[10];
  const float* w2   = (const float*)d_in[11];
  const float* b2   = (const float*)d_in[12];
  const float* w3   = (const float*)d_in[13];
  const float* b3   = (const float*)d_in[14];
  const float* w4   = (const float*)d_in[15];
  const float* b4   = (const float*)d_in[16];
  float* out = (float*)d_out;

  char* p = (char*)d_ws;
  unsigned short* H   = (unsigned short*)p; p += (size_t)(TSTEPS + 1) * BATCH * HID * 2;
  unsigned short* Xg  = (unsigned short*)p; p += (size_t)TSTEPS * BATCH * KIN * 2;
  unsigned int*  flags = (unsigned int*)p;  p += (size_t)TSTEPS * 4;
  unsigned short* Wc  = (unsigned short*)p; p += (size_t)3072 * KC * 2;
  unsigned short* w1b = (unsigned short*)p; p += (size_t)1024 * KFC * 2;
  unsigned short* w2b = (unsigned short*)p; p += (size_t)256 * FCN * 2;
  unsigned short* w3b = (unsigned short*)p; p += (size_t)1024 * KFC * 2;
  unsigned short* w4b = (unsigned short*)p; p += (size_t)256 * FCN * 2;
  unsigned short* a2b = (unsigned short*)p; p += (size_t)TSTEPS * BATCH * 64 * 2;
  unsigned short* a3b = (unsigned short*)p; p += (size_t)TSTEPS * BATCH * 64 * 2;

  if ((size_t)(p - (char*)d_ws) > ws_size) return;  // ws too small: fail loudly via absmax

  k_pack<<<TSTEPS, 256, 0, stream>>>(x, feat, aux1, aux2, aux3, Xg, H, a2b, a3b, flags);
  k_wconv<<<5632, 256, 0, stream>>>(w_ih, w_hh, w1, w2, w3, w4, Wc, w1b, w2b, w3b, w4b);
  k_gru<<<NWG + NFC, 192, 0, stream>>>(Wc, b_ih, b_hh, Xg, H, flags,
                                       a2b, a3b, w1b, w2b, w3b, w4b,
                                       b1, b2, b3, b4, out);
}